// Round 1
// baseline (1080.124 us; speedup 1.0000x reference)
//
#include <hip/hip_runtime.h>
#include <hip/hip_bf16.h>

#define NNODES 100000
#define NEDGES 1000000
#define MM 5          // M
#define WW 35         // W = 7*M
#define DD 3          // hidden depth

// padded LDS row strides (floats)
#define SROW 12       // start layer: 10 -> 12  (3 x float4)
#define HROW 36       // hidden/end:  35 -> 36  (9 x float4)

// per-net LDS layout (float offsets), all 16B-aligned
#define OFF_SW 0                       // 35*12  = 420
#define OFF_HW 420                     // 3*35*36= 3780
#define OFF_EW 4200                    // 5*36   = 180
#define OFF_SB 4380                    // 35
#define OFF_HB 4415                    // 105
#define OFF_EB 4520                    // 5 (+3 pad)
#define NET_STRIDE 4528                // floats; 18112 B (16B-aligned)
#define LDS_FLOATS (2 * NET_STRIDE)    // 36224 B

__device__ __forceinline__ float sigmoidf(float z) {
    return 1.0f / (1.0f + __expf(-z));
}

__global__ void __launch_bounds__(256) edge_kernel(
    const float* __restrict__ score,
    const int*   __restrict__ edge_idx,
    const float* __restrict__ outcome,
    const float* __restrict__ Rsw, const float* __restrict__ Rsb,
    const float* __restrict__ Rhw, const float* __restrict__ Rhb,
    const float* __restrict__ Rew, const float* __restrict__ Reb,
    const float* __restrict__ Psw, const float* __restrict__ Psb,
    const float* __restrict__ Phw, const float* __restrict__ Phb,
    const float* __restrict__ Pew, const float* __restrict__ Peb,
    float* __restrict__ agg, int* __restrict__ deg)
{
    __shared__ __align__(16) float lds[LDS_FLOATS];

    // zero entire LDS (covers all pads; pads must be 0.0, not garbage/NaN)
    for (int i = threadIdx.x; i < LDS_FLOATS; i += 256) lds[i] = 0.0f;
    __syncthreads();

    auto fill = [&](const float* sw, const float* sb, const float* hw, const float* hb,
                    const float* ew, const float* eb, int base) {
        for (int g = threadIdx.x; g < WW * 10; g += 256) {            // start w (35x10)
            int r = g / 10, c = g - r * 10;
            lds[base + OFF_SW + r * SROW + c] = sw[g];
        }
        for (int g = threadIdx.x; g < DD * WW * WW; g += 256) {       // hidden w (3x35x35)
            int l = g / (WW * WW);
            int rem = g - l * (WW * WW);
            int r = rem / WW, c = rem - r * WW;
            lds[base + OFF_HW + l * (WW * HROW) + r * HROW + c] = hw[g];
        }
        for (int g = threadIdx.x; g < MM * WW; g += 256) {            // end w, rows 0..4 only
            int r = g / WW, c = g - r * WW;
            lds[base + OFF_EW + r * HROW + c] = ew[g];
        }
        if (threadIdx.x < WW)      lds[base + OFF_SB + threadIdx.x] = sb[threadIdx.x];
        if (threadIdx.x < DD * WW) lds[base + OFF_HB + threadIdx.x] = hb[threadIdx.x];
        if (threadIdx.x < MM)      lds[base + OFF_EB + threadIdx.x] = eb[threadIdx.x];
    };
    fill(Rsw, Rsb, Rhw, Rhb, Rew, Reb, 0);
    fill(Psw, Psb, Phw, Phb, Pew, Peb, NET_STRIDE);
    __syncthreads();

    for (int e = blockIdx.x * 256 + threadIdx.x; e < NEDGES; e += gridDim.x * 256) {
        int idxv[10];
        #pragma unroll
        for (int j = 0; j < 10; ++j) idxv[j] = edge_idx[e * 10 + j];

        float xf[10];
        #pragma unroll
        for (int j = 0; j < 10; ++j) xf[j] = score[idxv[j]];

        const bool pos = outcome[e] > 0.0f;

        #pragma unroll
        for (int j = 0; j < 10; ++j) atomicAdd(&deg[idxv[j]], 1);

        #pragma unroll 1
        for (int dir = 0; dir < 2; ++dir) {
            // fwd uses R if pos else P; rev uses P if pos else R
            const bool useR = (dir == 0) ? pos : !pos;
            const float* net = &lds[useR ? 0 : NET_STRIDE];

            float xin[SROW];
            #pragma unroll
            for (int i = 0; i < 10; ++i) xin[i] = (dir == 0) ? xf[i] : xf[9 - i];
            xin[10] = 0.0f; xin[11] = 0.0f;

            float h[HROW];

            // ---- start layer: 35 x 10 ----
            #pragma unroll
            for (int j = 0; j < WW; ++j) {
                const float4* w4 = reinterpret_cast<const float4*>(net + OFF_SW + j * SROW);
                float acc = net[OFF_SB + j];
                #pragma unroll
                for (int q = 0; q < SROW / 4; ++q) {
                    float4 wv = w4[q];
                    acc += wv.x * xin[4*q+0] + wv.y * xin[4*q+1]
                         + wv.z * xin[4*q+2] + wv.w * xin[4*q+3];
                }
                h[j] = fmaxf(acc, 0.0f);
            }
            h[WW] = 0.0f;   // pad lane stays 0 across all layers

            // ---- hidden layers: 3 x (35 x 35) ----
            #pragma unroll 1
            for (int l = 0; l < DD; ++l) {
                const float* wbase = net + OFF_HW + l * (WW * HROW);
                const float* bbase = net + OFF_HB + l * WW;
                float ho[WW];
                #pragma unroll
                for (int j = 0; j < WW; ++j) {
                    const float4* w4 = reinterpret_cast<const float4*>(wbase + j * HROW);
                    float acc = bbase[j];
                    #pragma unroll
                    for (int q = 0; q < HROW / 4; ++q) {
                        float4 wv = w4[q];
                        acc += wv.x * h[4*q+0] + wv.y * h[4*q+1]
                             + wv.z * h[4*q+2] + wv.w * h[4*q+3];
                    }
                    ho[j] = fmaxf(acc, 0.0f);
                }
                #pragma unroll
                for (int j = 0; j < WW; ++j) h[j] = ho[j];
            }

            // ---- end layer (5 rows) + sigmoid + signed scatter ----
            const float sgn = ((dir == 0) == pos) ? 1.0f : -1.0f;
            #pragma unroll
            for (int k = 0; k < MM; ++k) {
                const float4* w4 = reinterpret_cast<const float4*>(net + OFF_EW + k * HROW);
                float acc = net[OFF_EB + k];
                #pragma unroll
                for (int q = 0; q < HROW / 4; ++q) {
                    float4 wv = w4[q];
                    acc += wv.x * h[4*q+0] + wv.y * h[4*q+1]
                         + wv.z * h[4*q+2] + wv.w * h[4*q+3];
                }
                float val = sgn * sigmoidf(acc);
                int tgt = (dir == 0) ? idxv[k] : idxv[5 + k];
                unsafeAtomicAdd(&agg[tgt], val);
            }
        }
    }
}

__global__ void __launch_bounds__(256) degmax_kernel(const int* __restrict__ deg,
                                                     int* __restrict__ degmax)
{
    int m = 0;
    for (int i = blockIdx.x * blockDim.x + threadIdx.x; i < NNODES;
         i += gridDim.x * blockDim.x)
        m = max(m, deg[i]);
    #pragma unroll
    for (int off = 32; off; off >>= 1) m = max(m, __shfl_down(m, off));
    __shared__ int sm[4];
    if ((threadIdx.x & 63) == 0) sm[threadIdx.x >> 6] = m;
    __syncthreads();
    if (threadIdx.x == 0) {
        int mm = sm[0];
        #pragma unroll
        for (int w = 1; w < 4; ++w) mm = max(mm, sm[w]);
        atomicMax(degmax, mm);
    }
}

__global__ void __launch_bounds__(256) stats_kernel(const float* __restrict__ score,
                                                    const float* __restrict__ agg,
                                                    const int* __restrict__ degmax,
                                                    float* __restrict__ stats)
{
    const float scale = 2.0f / (float)(*degmax);
    float s = 0.0f, s2 = 0.0f;
    for (int i = blockIdx.x * blockDim.x + threadIdx.x; i < NNODES;
         i += gridDim.x * blockDim.x) {
        float v = fmaf(agg[i], scale, score[i]);
        s += v;
        s2 = fmaf(v, v, s2);
    }
    #pragma unroll
    for (int off = 32; off; off >>= 1) {
        s  += __shfl_down(s, off);
        s2 += __shfl_down(s2, off);
    }
    __shared__ float ssum[4], ssq[4];
    if ((threadIdx.x & 63) == 0) { ssum[threadIdx.x >> 6] = s; ssq[threadIdx.x >> 6] = s2; }
    __syncthreads();
    if (threadIdx.x == 0) {
        float a = 0.0f, b = 0.0f;
        #pragma unroll
        for (int w = 0; w < 4; ++w) { a += ssum[w]; b += ssq[w]; }
        unsafeAtomicAdd(&stats[0], a);
        unsafeAtomicAdd(&stats[1], b);
    }
}

__global__ void __launch_bounds__(256) finalize_kernel(const float* __restrict__ score,
                                                       const float* __restrict__ agg,
                                                       const int* __restrict__ degmax,
                                                       const float* __restrict__ stats,
                                                       float* __restrict__ out)
{
    const float scale = 2.0f / (float)(*degmax);
    const float sum = stats[0], sumsq = stats[1];
    const float mean = sum * (1.0f / NNODES);
    // sum((s-mean)^2) = sumsq - sum*mean
    const float rn = 1.0f / sqrtf(sumsq - sum * mean);
    for (int i = blockIdx.x * blockDim.x + threadIdx.x; i < NNODES;
         i += gridDim.x * blockDim.x) {
        float v = fmaf(agg[i], scale, score[i]);
        out[i] = (v - mean) * rn;
    }
}

extern "C" void kernel_launch(void* const* d_in, const int* in_sizes, int n_in,
                              void* d_out, int out_size, void* d_ws, size_t ws_size,
                              hipStream_t stream)
{
    const float* score    = (const float*)d_in[0];
    const int*   edge_idx = (const int*)  d_in[1];
    const float* outcome  = (const float*)d_in[2];
    const float* Rsw = (const float*)d_in[3];
    const float* Rsb = (const float*)d_in[4];
    const float* Rhw = (const float*)d_in[5];
    const float* Rhb = (const float*)d_in[6];
    const float* Rew = (const float*)d_in[7];
    const float* Reb = (const float*)d_in[8];
    const float* Psw = (const float*)d_in[9];
    const float* Psb = (const float*)d_in[10];
    const float* Phw = (const float*)d_in[11];
    const float* Phb = (const float*)d_in[12];
    const float* Pew = (const float*)d_in[13];
    const float* Peb = (const float*)d_in[14];
    float* out = (float*)d_out;

    // workspace layout: agg[N] f32 | deg[N] i32 | stats[2] f32 | degmax i32
    float* agg    = (float*)d_ws;
    int*   deg    = (int*)  ((char*)d_ws + (size_t)NNODES * 4);
    float* stats  = (float*)((char*)d_ws + (size_t)2 * NNODES * 4);
    int*   degmax = (int*)  ((char*)d_ws + ((size_t)2 * NNODES + 2) * 4);

    hipMemsetAsync(d_ws, 0, ((size_t)2 * NNODES + 3) * 4, stream);

    edge_kernel<<<2048, 256, 0, stream>>>(score, edge_idx, outcome,
                                          Rsw, Rsb, Rhw, Rhb, Rew, Reb,
                                          Psw, Psb, Phw, Phb, Pew, Peb,
                                          agg, deg);

    const int nb = (NNODES + 255) / 256;
    degmax_kernel  <<<nb, 256, 0, stream>>>(deg, degmax);
    stats_kernel   <<<nb, 256, 0, stream>>>(score, agg, degmax, stats);
    finalize_kernel<<<nb, 256, 0, stream>>>(score, agg, degmax, stats, out);
}